// Round 11
// baseline (1441.471 us; speedup 1.0000x reference)
//
#include <hip/hip_runtime.h>
#include <hip/hip_fp16.h>

#define BB 128
#define TT 500
#define HH 512
#define TWOH 1024
#define KB 16  // k-tiles of 32

typedef _Float16 f16x8 __attribute__((ext_vector_type(8)));
typedef float f32x4 __attribute__((ext_vector_type(4)));
typedef unsigned long long u64;

// ws: u16 1 MiB | hx u32 [8 g][2 par][16 m][512 k] (512 KiB)
// hx word = (tag16 << 16) | fp16 h[m][k]   (tag = step, 0..500; 0xFFFF = inv)
#define WS_U16_HALVES (TWOH * HH)
#define HX_WORDS (8 * 2 * 16 * HH)

__global__ void prep_kernel(const float* __restrict__ u,
                            const float* __restrict__ ht,
                            __half* __restrict__ u16,
                            unsigned* __restrict__ hx) {
  int i = blockIdx.x * blockDim.x + threadIdx.x;
  if (i < WS_U16_HALVES) u16[i] = __float2half(u[i]);
  if (i < HX_WORDS) {
    int g = i >> 14, rem = i & 16383;
    int par = rem >> 13, m = (rem >> 9) & 15, k = rem & 511;
    unsigned val;
    if (par == 0) {  // h_0, tag 0 in high halfword
      int R = g * 16 + m;
      val = (unsigned)__half_as_ushort(__float2half(ht[(size_t)R * HH + k]));
    } else {
      val = 0xFFFF0000u;  // sentinel (never matches; replay-stale safe)
    }
    hx[i] = val;
  }
}

#define TAGMASK 0xFFFF0000FFFF0000ull

// 64 blocks x 256 threads (4 waves). Block b: group g=b>>3 (16 batch rows),
// col-slice s=b&7 (64 cols, both gates). One chain-phase per step. Fused
// tag16+fp16 dword protocol: the cooperative tagged read IS the flag poll
// AND the payload fetch. R11: prefetch issued AFTER the h stores (producers
// have fired by arrival -> first check hits) and BEFORE the output stores
// (counted-vmcnt check wait doesn't drain HBM write-acks).
__global__ __launch_bounds__(256, 1) void ligru_mfma(
    const float* __restrict__ wx, const __half* __restrict__ u16,
    const float* __restrict__ ht, const float* __restrict__ mask,
    float* __restrict__ out, unsigned* __restrict__ hx) {
  const int tid = threadIdx.x;
  const int lane = tid & 63;
  const int w = tid >> 6;
  const int l15 = lane & 15;
  const int q = lane >> 4;
  const int b = blockIdx.x;
  const int g = b >> 3;
  const int s = b & 7;
  const int row0 = g * 16;
  const int j = s * 64 + w * 16 + l15;  // this lane's hidden col

  __shared__ alignas(16) char hsm[2][16 * 1024];  // [par][m][k] fp16, XOR-swz

  // B-frags (u), persistent (128 VGPR). nt0: gate row j (at); nt1: row 512+j.
  f16x8 bf[KB][2];
#pragma unroll
  for (int kb = 0; kb < KB; ++kb) {
    bf[kb][0] = *(const f16x8*)(u16 + (size_t)j * HH + kb * 32 + q * 8);
    bf[kb][1] = *(const f16x8*)(u16 + (size_t)(HH + j) * HH + kb * 32 + q * 8);
  }

  // per-lane persistent state: rows m=4q+r, col j; fp32 master h
  float hreg[4], mreg[4];
#pragma unroll
  for (int r = 0; r < 4; ++r) {
    size_t off = (size_t)(row0 + 4 * q + r) * HH + j;
    mreg[r] = mask[off];
    hreg[r] = ht[off];
  }

  const size_t BTH = (size_t)BB * TT * HH;
  float* out_h = out;
  float* out_z = out + BTH;
  float* out_a = out + 2 * BTH;
  float* out_hc = out + 3 * BTH;

  const u64* hxg = (const u64*)hx + ((size_t)g << 13);  // [2 par][4096 qw]

  // initial fetch: h(0), parity 0, written by prep with tag 0
  u64 qw[16];
#pragma unroll
  for (int pp = 0; pp < 16; ++pp)
    qw[pp] = __hip_atomic_load(hxg + pp * 256 + tid, __ATOMIC_RELAXED,
                               __HIP_MEMORY_SCOPE_AGENT);

  for (int t = 0; t < TT; ++t) {
    const int par = t & 1;

    // wx loads for this step (h-independent; in flight across the check)
    float wxa[4], wxz[4];
#pragma unroll
    for (int r = 0; r < 4; ++r) {
      size_t base = ((size_t)(row0 + 4 * q + r) * TT + t) * TWOH + j;
      wxa[r] = wx[base];
      wxz[r] = wx[base + HH];
    }

    // ---- tagged check + retry (first test is on the late prefetch, which
    // was issued after the previous step's h stores -> usually fresh)
    {
      const u64* src = hxg + par * 4096 + tid;
      const u64 tagp = ((u64)(unsigned)t << 48) | ((u64)(unsigned)t << 16);
      bool ok = true;
#pragma unroll
      for (int pp = 0; pp < 16; ++pp) ok &= ((qw[pp] & TAGMASK) == tagp);
      int bail = 0;
      while (!__all(ok)) {
        __builtin_amdgcn_s_sleep(1);
#pragma unroll
        for (int pp = 0; pp < 16; ++pp)
          qw[pp] = __hip_atomic_load(src + pp * 256, __ATOMIC_RELAXED,
                                     __HIP_MEMORY_SCOPE_AGENT);
        ok = true;
#pragma unroll
        for (int pp = 0; pp < 16; ++pp) ok &= ((qw[pp] & TAGMASK) == tagp);
        if (++bail > (1 << 15)) break;
      }
    }

    // ---- stage payload halves into XOR-swizzled LDS
    {
      char* dst = hsm[par];
#pragma unroll
      for (int pp = 0; pp < 16; ++pp) {
        unsigned d0 = (unsigned)qw[pp], d1 = (unsigned)(qw[pp] >> 32);
        unsigned pk = (d0 & 0xFFFFu) | (d1 << 16);
        *(unsigned*)(dst + ((pp * 1024 + tid * 4) ^ ((pp & 7) << 4))) = pk;
      }
    }
    __syncthreads();

    // ---- MFMA: A row=l15, k-chunk q from LDS; both gate tiles
    f32x4 acc0 = {0.f, 0.f, 0.f, 0.f}, acc1 = {0.f, 0.f, 0.f, 0.f};
#pragma unroll
    for (int kb = 0; kb < KB; ++kb) {
      int off = (l15 * 1024 + kb * 64 + q * 16) ^ ((l15 & 7) << 4);
      f16x8 af = *(const f16x8*)(hsm[par] + off);
      acc0 = __builtin_amdgcn_mfma_f32_16x16x32_f16(af, bf[kb][0], acc0, 0, 0, 0);
      acc1 = __builtin_amdgcn_mfma_f32_16x16x32_f16(af, bf[kb][1], acc1, 0, 0, 0);
    }

    // ---- epilogue: tagged h stores FIRST (the producer side of the step)
    unsigned* hd = hx + ((size_t)(g * 2 + (par ^ 1)) << 13);
    const unsigned tg = (unsigned)(t + 1) << 16;
    float atv[4], ztv[4], hcv[4];
#pragma unroll
    for (int r = 0; r < 4; ++r) {
      float at = acc0[r] + wxa[r];
      float zp = acc1[r] + wxz[r];
      float zt = 1.f / (1.f + __expf(-zp));
      float hc = fmaxf(at, 0.f) * mreg[r];
      float hn = hreg[r] * zt + (1.f - zt) * hc;
      hreg[r] = hn;
      __hip_atomic_store(hd + (4 * q + r) * HH + j,
                         tg | (unsigned)__half_as_ushort(__float2half(hn)),
                         __ATOMIC_RELAXED, __HIP_MEMORY_SCOPE_AGENT);
      atv[r] = at;
      ztv[r] = zt;
      hcv[r] = hc;
    }

    // ---- prefetch next parity NOW: after the h stores (peers' stores land
    // within the load flight time), before the output stores (so the next
    // check's wait is a counted vmcnt that leaves them outstanding).
    if (t + 1 < TT) {
      const u64* srcn = hxg + (par ^ 1) * 4096 + tid;
#pragma unroll
      for (int pp = 0; pp < 16; ++pp)
        qw[pp] = __hip_atomic_load(srcn + pp * 256, __ATOMIC_RELAXED,
                                   __HIP_MEMORY_SCOPE_AGENT);
    }

    // ---- bulk outputs: fire-and-forget, newest in the vmcnt queue
#pragma unroll
    for (int r = 0; r < 4; ++r) {
      size_t oi = ((size_t)(row0 + 4 * q + r) * TT + t) * HH + j;
      __builtin_nontemporal_store(hreg[r], &out_h[oi]);
      __builtin_nontemporal_store(ztv[r], &out_z[oi]);
      __builtin_nontemporal_store(atv[r], &out_a[oi]);
      __builtin_nontemporal_store(hcv[r], &out_hc[oi]);
    }
    // hsm[par^1] is written next step only after this step's barrier.
  }
}

extern "C" void kernel_launch(void* const* d_in, const int* in_sizes, int n_in,
                              void* d_out, int out_size, void* d_ws,
                              size_t ws_size, hipStream_t stream) {
  const float* wx = (const float*)d_in[0];
  const float* u = (const float*)d_in[1];
  const float* ht = (const float*)d_in[2];
  const float* mask = (const float*)d_in[3];
  float* out = (float*)d_out;

  __half* u16 = (__half*)d_ws;
  unsigned* hx = (unsigned*)(u16 + WS_U16_HALVES);

  hipLaunchKernelGGL(prep_kernel, dim3(2048), dim3(256), 0, stream, u, ht, u16,
                     hx);
  hipLaunchKernelGGL(ligru_mfma, dim3(64), dim3(256), 0, stream, wx, u16, ht,
                     mask, out, hx);
}